// Round 5
// baseline (187.190 us; speedup 1.0000x reference)
//
#include <hip/hip_runtime.h>

#define BATCH 8
#define NPTS  12000
#define FDIM  128
#define SDIM  16
#define ODIM  128
#define KDIM  (SDIM * FDIM)      // 2048
#define MTOT  (BATCH * NPTS)     // 96000

#define BM 192                   // block rows (6 waves x 64)
#define BK 32                    // K-step: row = 64 B = 4 x 16B chunks

#define NTILES 63                // ceil(12000 / 192) -> 504 blocks = ~2/CU exactly
#define XELEMS (BATCH * NPTS * FDIM)   // 12,288,000
#define WELEMS (ODIM * KDIM)           // 262,144
#define XBYTES ((size_t)XELEMS * 2)
#define WBYTES ((size_t)WELEMS * 2)

typedef __bf16 bf16x4 __attribute__((ext_vector_type(4)));
typedef __bf16 bf16x8 __attribute__((ext_vector_type(8)));
typedef float  f32x4  __attribute__((ext_vector_type(4)));
typedef float  f32x8  __attribute__((ext_vector_type(8)));

#define AS1(p) ((const __attribute__((address_space(1))) void*)(p))
#define AS3(p) ((__attribute__((address_space(3))) void*)(p))

// ---------------- pre-pass: fp32 -> bf16, no-loop / branch-free / wide ----------
#define CVT_XBLK 6000            // 6000 * 256 * 8 = 12,288,000 = XELEMS
#define CVT_WBLK 128             //  128 * 256 * 8 =    262,144 = WELEMS
#define CVT_BPB  750             // x blocks per batch (6000 / 8)

__global__ __launch_bounds__(256)
void cvt_f32_bf16(const float* __restrict__ x, const float* __restrict__ W,
                  __bf16* __restrict__ xb, __bf16* __restrict__ Wb) {
    const int blk = blockIdx.x;
    const float* __restrict__ src;
    __bf16* __restrict__ dst;
    size_t base;
    if (blk < CVT_XBLK) {
        const int b = blk & 7;               // batch -> XCD (matches GEMM)
        const int c = blk >> 3;              // chunk within batch [0, 750)
        base = ((size_t)b * CVT_BPB + c) * (256 * 8) + (size_t)threadIdx.x * 8;
        src = x;  dst = xb;
    } else {
        base = (size_t)(blk - CVT_XBLK) * (256 * 8) + (size_t)threadIdx.x * 8;
        src = W;  dst = Wb;
    }
    const f32x8 v = *reinterpret_cast<const f32x8*>(src + base);
    bf16x8 h;
#pragma unroll
    for (int e = 0; e < 8; ++e) h[e] = (__bf16)v[e];
    *reinterpret_cast<bf16x8*>(dst + base) = h;
}

// ---------------- main GEMM: 192x128 tile, 6 waves of 64x64, BK=32 ---------------
// Same verified 2-barrier / counted-vmcnt schedule as the 63.7us kernel; changes:
//   - wave tiles 64x64 (acc[4][4]) -> 32 FLOP per LDS byte (vs 21.3 at 32x64):
//     the LDS read port (~12 cyc/ds_read_b128, m134) was ~70% busy and was the
//     co-bottleneck; this cuts LDS traffic 1.5x.
//   - BM=192 -> 63 M-tiles x 8 batches = 504 blocks ~= 2/CU: no dispatch tail.
//   - LDS 52 KB (As 24 + Ws 16 + idxS 12) -> 2-3 blocks/CU resident.
// BK=32 swizzle: rows are 64 B = 4 chunks of 16 B; phys_chunk = chunk ^ ((row>>2)&3).
// DMA (1 KB = 16 rows) writes LDS linearly, so the SOURCE address is inverse-
// swizzled per-lane (G21); ds_read applies the same XOR -> 2-way (free) per
// quarter-wave phase, same model as the verified BK=64 swizzle.
// vmcnt: per tile each wave issues 2 A-DMAs; waves 0-3 also 2 W-DMAs ->
// per-wave counted wait vmcnt(4) / vmcnt(2) (vmcnt is per-wave).
__global__ __launch_bounds__(384, 3)
void spiral_gemm_bf16(const __bf16* __restrict__ xb,    // (B, N, F) bf16 (ws)
                      const __bf16* __restrict__ Wb,    // (OUT, K) bf16 (ws)
                      const float*  __restrict__ bias,  // (OUT,) fp32
                      const int*    __restrict__ idx,   // (N, S) int32
                      const float*  __restrict__ zp,    // (N,) fp32
                      float*        __restrict__ out)   // (B, N, OUT) fp32
{
    __shared__ __bf16 As[2][BM * BK];    // 2 x 12 KB
    __shared__ __bf16 Ws[2][ODIM * BK];  // 2 x  8 KB
    __shared__ int    idxS[BM * SDIM];   // 12 KB  -> 52 KB total

    const int tid   = threadIdx.x;
    const int wave  = tid >> 6;                // 0..5
    const int lane  = tid & 63;
    const int batch = blockIdx.x & 7;          // round-robin -> same XCD per batch
    const int n0    = (blockIdx.x >> 3) * BM;

    const int lrow16 = lane >> 2;              // row within the 16-row DMA group
    const int clog   = (lane & 3) ^ ((lane >> 4) & 3); // inverse-swizzled chunk

    const __bf16* xbase = xb + (size_t)batch * (NPTS * FDIM);

    // --- preload all gather indices for this block's 192 rows into LDS ---
    {
        const int row  = tid >> 1, half = tid & 1;    // 384 thr -> 192 rows x 2
        const int n    = n0 + row;
        const int nrow = n < NPTS ? n : NPTS - 1;
        const int4* s4 = reinterpret_cast<const int4*>(idx + nrow * SDIM + half * 8);
        int4* d4       = reinterpret_cast<int4*>(&idxS[row * SDIM + half * 8]);
        d4[0] = s4[0];
        d4[1] = s4[1];
    }
    __syncthreads();   // full drain OK here, once

    int rrow[2];
#pragma unroll
    for (int p = 0; p < 2; ++p) rrow[p] = wave * 32 + p * 16 + lrow16;

    int gCur[2], gNext[2];
#pragma unroll
    for (int p = 0; p < 2; ++p) gCur[p] = idxS[rrow[p] * SDIM + 0];

    // --- DMA helpers: A = 12 instrs (16 rows each), wave w owns rows [32w,32w+32)
    //     W = 8 instrs, waves 0-3 own rows [32w,32w+32) of ODIM=128 ---
    auto issueA = [&](int buf, int f0, const int* g) {
#pragma unroll
        for (int p = 0; p < 2; ++p) {
            const int r0 = wave * 32 + p * 16;
            const __bf16* ga = xbase + (size_t)g[p] * FDIM + f0 + clog * 8;
            __builtin_amdgcn_global_load_lds(AS1(ga), AS3(&As[buf][r0 * BK]), 16, 0, 0);
        }
    };
    auto issueW = [&](int buf, int kt) {
        if (wave < 4) {
#pragma unroll
            for (int p = 0; p < 2; ++p) {
                const int r0 = wave * 32 + p * 16;
                const __bf16* gw = Wb + (size_t)(r0 + lrow16) * KDIM + kt * BK + clog * 8;
                __builtin_amdgcn_global_load_lds(AS1(gw), AS3(&Ws[buf][r0 * BK]), 16, 0, 0);
            }
        }
    };
    auto waitA = [&]() {
        if (wave < 4) { asm volatile("s_waitcnt vmcnt(4)" ::: "memory"); }
        else          { asm volatile("s_waitcnt vmcnt(2)" ::: "memory"); }
    };

    f32x4 acc[4][4];
#pragma unroll
    for (int i = 0; i < 4; ++i)
#pragma unroll
        for (int j = 0; j < 4; ++j)
            acc[i][j] = f32x4{0.f, 0.f, 0.f, 0.f};

    const int wm   = (wave >> 1) * 64;         // 0,64,128
    const int wn   = (wave & 1) * 64;          // 0,64
    const int lrow = lane & 15;
    const int quad = lane >> 4;
    const int ph   = quad ^ ((lrow >> 2) & 3); // swizzled chunk for ds_read

    auto compute = [&](int buf) {
        bf16x8 a[4], b[4];
#pragma unroll
        for (int i = 0; i < 4; ++i)
            a[i] = *reinterpret_cast<const bf16x8*>(
                &As[buf][(wm + i * 16 + lrow) * BK + ph * 8]);
#pragma unroll
        for (int j = 0; j < 4; ++j)
            b[j] = *reinterpret_cast<const bf16x8*>(
                &Ws[buf][(wn + j * 16 + lrow) * BK + ph * 8]);
#pragma unroll
        for (int i = 0; i < 4; ++i)
#pragma unroll
            for (int j = 0; j < 4; ++j)
                acc[i][j] = __builtin_amdgcn_mfma_f32_16x16x32_bf16(
                    a[i], b[j], acc[i][j], 0, 0, 0);
    };

    // preamble: kt=0 (s=0, f0=0) -> buf0
    issueA(0, 0, gCur);
    issueW(0, 0);

    for (int t = 0; t < 16; ++t) {             // s = t; kt = 4t .. 4t+3
        // sub0: compute 4t (buf0); issue 4t+1 (f0=32) -> buf1
        issueA(1, 32, gCur);  issueW(1, 4 * t + 1);
        waitA();
        asm volatile("s_barrier" ::: "memory");
        if (t < 15) {
#pragma unroll
            for (int p = 0; p < 2; ++p)
                gNext[p] = idxS[rrow[p] * SDIM + t + 1];  // lgkm, hidden by compute
        }
        compute(0);
        asm volatile("s_barrier" ::: "memory");

        // sub1: compute 4t+1 (buf1); issue 4t+2 (f0=64) -> buf0
        issueA(0, 64, gCur);  issueW(0, 4 * t + 2);
        waitA();
        asm volatile("s_barrier" ::: "memory");
        compute(1);
        asm volatile("s_barrier" ::: "memory");

        // sub2: compute 4t+2 (buf0); issue 4t+3 (f0=96) -> buf1
        issueA(1, 96, gCur);  issueW(1, 4 * t + 3);
        waitA();
        asm volatile("s_barrier" ::: "memory");
        compute(0);
        asm volatile("s_barrier" ::: "memory");

        // sub3: compute 4t+3 (buf1); issue 4t+4 (s=t+1, f0=0, gNext) -> buf0
        if (t < 15) {
            issueA(0, 0, gNext);  issueW(0, 4 * t + 4);
            waitA();
        } else {
            asm volatile("s_waitcnt vmcnt(0)" ::: "memory");
        }
        asm volatile("s_barrier" ::: "memory");
        compute(1);
        asm volatile("s_barrier" ::: "memory");
#pragma unroll
        for (int p = 0; p < 2; ++p) gCur[p] = gNext[p];
    }

    // epilogue: bias + relu + zero_padding; C/D: col=lane&15, row=quad*4+reg
#pragma unroll
    for (int i = 0; i < 4; ++i) {
#pragma unroll
        for (int r = 0; r < 4; ++r) {
            const int row = wm + i * 16 + quad * 4 + r;
            const int n   = n0 + row;
            if (n < NPTS) {
                const float z = zp[n];
                float* orow   = out + ((size_t)batch * NPTS + n) * ODIM;
#pragma unroll
                for (int j = 0; j < 4; ++j) {
                    const int col = wn + j * 16 + lrow;
                    float v = acc[i][j][r] + bias[col];
                    v = fmaxf(v, 0.f);
                    orow[col] = v * z;
                }
            }
        }
    }
}

// ---------------- fallback: fp32 direct, no ws (round-2 kernel, BM=128) ---------
#define LDA 72
#define BMF 128
__global__ __launch_bounds__(256, 2)
void spiral_gemm_fp32(const float* __restrict__ x, const float* __restrict__ W,
                      const float* __restrict__ bias, const int* __restrict__ idx,
                      const float* __restrict__ zp, float* __restrict__ out)
{
    __shared__ __bf16 Asf[BMF * LDA];
    __shared__ __bf16 Wsf[ODIM * LDA];
    const int tid = threadIdx.x, wave = tid >> 6, lane = tid & 63;
    const int m0 = blockIdx.x * BMF;
    const int srow = tid >> 3, schunk = tid & 7;
    int a_n[4]; const float* a_xb[4];
#pragma unroll
    for (int p = 0; p < 4; ++p) {
        int m = m0 + srow + p * 32, bb = m / NPTS;
        a_n[p] = m - bb * NPTS; a_xb[p] = x + (size_t)bb * (NPTS * FDIM);
    }
    f32x4 acc[4][4];
#pragma unroll
    for (int i = 0; i < 4; ++i)
#pragma unroll
        for (int j = 0; j < 4; ++j) acc[i][j] = f32x4{0.f,0.f,0.f,0.f};
    const int wm = (wave >> 1) * 64, wn = (wave & 1) * 64;
    const int lrow = lane & 15, quad = lane >> 4;
    for (int kt = 0; kt < KDIM / 64; ++kt) {
        const int s = kt >> 1, f0 = (kt & 1) * 64;
        __syncthreads();
#pragma unroll
        for (int p = 0; p < 4; ++p) {
            const int r = srow + p * 32;
            const int g = idx[a_n[p] * SDIM + s];
            const f32x8 v = *reinterpret_cast<const f32x8*>(
                a_xb[p] + (size_t)g * FDIM + f0 + schunk * 8);
            bf16x8 h;
#pragma unroll
            for (int e = 0; e < 8; ++e) h[e] = (__bf16)v[e];
            *reinterpret_cast<bf16x8*>(&Asf[r * LDA + schunk * 8]) = h;
            const f32x8 w = *reinterpret_cast<const f32x8*>(
                W + (size_t)r * KDIM + kt * 64 + schunk * 8);
            bf16x8 hw;
#pragma unroll
            for (int e = 0; e < 8; ++e) hw[e] = (__bf16)w[e];
            *reinterpret_cast<bf16x8*>(&Wsf[r * LDA + schunk * 8]) = hw;
        }
        __syncthreads();
#pragma unroll
        for (int kk = 0; kk < 2; ++kk) {
            const int koff = kk * 32 + quad * 8;
            bf16x8 a[4], b[4];
#pragma unroll
            for (int i = 0; i < 4; ++i)
                a[i] = *reinterpret_cast<const bf16x8*>(&Asf[(wm + i*16 + lrow)*LDA + koff]);
#pragma unroll
            for (int j = 0; j < 4; ++j)
                b[j] = *reinterpret_cast<const bf16x8*>(&Wsf[(wn + j*16 + lrow)*LDA + koff]);
#pragma unroll
            for (int i = 0; i < 4; ++i)
#pragma unroll
                for (int j = 0; j < 4; ++j)
                    acc[i][j] = __builtin_amdgcn_mfma_f32_16x16x32_bf16(a[i], b[j], acc[i][j], 0,0,0);
        }
    }
#pragma unroll
    for (int i = 0; i < 4; ++i)
#pragma unroll
        for (int r = 0; r < 4; ++r) {
            const int row = wm + i * 16 + quad * 4 + r;
            const int m = m0 + row, bb = m / NPTS, nnn = m - bb * NPTS;
            const float z = zp[nnn];
            float* orow = out + (size_t)m * ODIM;
#pragma unroll
            for (int j = 0; j < 4; ++j) {
                const int col = wn + j * 16 + lrow;
                float v = acc[i][j][r] + bias[col];
                orow[col] = fmaxf(v, 0.f) * z;
            }
        }
}

extern "C" void kernel_launch(void* const* d_in, const int* in_sizes, int n_in,
                              void* d_out, int out_size, void* d_ws, size_t ws_size,
                              hipStream_t stream) {
    const float* x    = (const float*)d_in[0];
    const float* W    = (const float*)d_in[1];
    const float* bias = (const float*)d_in[2];
    const int*   idx  = (const int*)d_in[3];
    const float* zp   = (const float*)d_in[4];
    float*       out  = (float*)d_out;

    if (ws_size >= XBYTES + WBYTES) {
        __bf16* xb = (__bf16*)d_ws;
        __bf16* Wb = (__bf16*)((char*)d_ws + XBYTES);
        cvt_f32_bf16<<<dim3(CVT_XBLK + CVT_WBLK), dim3(256), 0, stream>>>(x, W, xb, Wb);
        spiral_gemm_bf16<<<dim3(BATCH * NTILES), dim3(384), 0, stream>>>(
            xb, Wb, bias, idx, zp, out);
    } else {
        spiral_gemm_fp32<<<dim3(MTOT / BMF), dim3(256), 0, stream>>>(
            x, W, bias, idx, zp, out);
    }
}